// Round 1
// 919.200 us; speedup vs baseline: 1.0711x; 1.0711x over previous
//
#include <hip/hip_runtime.h>
#include <math.h>

namespace {

typedef unsigned short bf16_t;
typedef __bf16  bf16x8_t __attribute__((ext_vector_type(8)));
typedef float   f32x4_t  __attribute__((ext_vector_type(4)));
typedef unsigned int u32x4 __attribute__((ext_vector_type(4)));

constexpr int G     = 4096;      // BS*E
constexpr int GA    = 32768;     // G*A
constexpr int WDIM  = 300;
constexpr int KPAD  = 320;
constexpr int HDIM  = 1024;
constexpr int NNODE = 9;
constexpr int MROWS = G * NNODE; // 36864
constexpr int TE_   = 8;
constexpr int TA_   = 4;
constexpr int V_    = 30522;
constexpr int VP    = 30592;     // 239*128
constexpr int PROJW = 1024;

__device__ __forceinline__ float bf2f(bf16_t b) {
    union { unsigned int u; float f; } v; v.u = ((unsigned int)b) << 16; return v.f;
}
__device__ __forceinline__ bf16_t f2bf(float f) {
    union { float f; unsigned int u; } v; v.f = f;
    unsigned int r = v.u + 0x7FFFu + ((v.u >> 16) & 1u);   // RNE
    return (bf16_t)(r >> 16);
}

// =====================================================================
// Generic 128x128-tile bf16 MFMA GEMM (validated R3/R4): C = A[M,K] @ B[N,K]^T
// MODE 0: C bf16 (vocab projection)   MODE 2: C fp32 with elu (final out)
// =====================================================================
template<int MODE>
__global__ __launch_bounds__(256)
void mfma_gemm(const bf16_t* __restrict__ A, const bf16_t* __restrict__ B,
               void* __restrict__ Cv, int lda, int ldb, int ldc, int K)
{
    __shared__ bf16_t As[128 * 32];
    __shared__ bf16_t Bs[128 * 32];

    const int tid  = threadIdx.x;
    const int w    = tid >> 6;
    const int lane = tid & 63;
    const int wr = w >> 1, wc = w & 1;
    const int lr = lane & 15;
    const int lk = lane >> 4;
    const int m0 = blockIdx.x * 128, n0 = blockIdx.y * 128;

    const int r0 = tid >> 2;
    const int cc = (tid & 3) * 8;
    const bf16_t* Arow0 = A + (size_t)(m0 + r0) * lda + cc;
    const bf16_t* Arow1 = Arow0 + (size_t)64 * lda;
    const bf16_t* Brow0 = B + (size_t)(n0 + r0) * ldb + cc;
    const bf16_t* Brow1 = Brow0 + (size_t)64 * ldb;

    f32x4_t acc[4][4];
#pragma unroll
    for (int i = 0; i < 4; ++i)
#pragma unroll
        for (int j = 0; j < 4; ++j) acc[i][j] = {0.f, 0.f, 0.f, 0.f};

    for (int k0 = 0; k0 < K; k0 += 32) {
        const uint4 a0 = *(const uint4*)(Arow0 + k0);
        const uint4 a1 = *(const uint4*)(Arow1 + k0);
        const uint4 b0 = *(const uint4*)(Brow0 + k0);
        const uint4 b1 = *(const uint4*)(Brow1 + k0);
        __syncthreads();
        *(uint4*)&As[r0 * 32 + cc]        = a0;
        *(uint4*)&As[(r0 + 64) * 32 + cc] = a1;
        *(uint4*)&Bs[r0 * 32 + cc]        = b0;
        *(uint4*)&Bs[(r0 + 64) * 32 + cc] = b1;
        __syncthreads();

        bf16x8_t af[4], bfr[4];
#pragma unroll
        for (int i = 0; i < 4; ++i) {
            af[i]  = *(const bf16x8_t*)&As[(wr * 64 + i * 16 + lr) * 32 + lk * 8];
            bfr[i] = *(const bf16x8_t*)&Bs[(wc * 64 + i * 16 + lr) * 32 + lk * 8];
        }
#pragma unroll
        for (int mi = 0; mi < 4; ++mi)
#pragma unroll
            for (int ni = 0; ni < 4; ++ni)
                acc[mi][ni] = __builtin_amdgcn_mfma_f32_16x16x32_bf16(
                    af[mi], bfr[ni], acc[mi][ni], 0, 0, 0);
    }

#pragma unroll
    for (int mi = 0; mi < 4; ++mi) {
#pragma unroll
        for (int ni = 0; ni < 4; ++ni) {
            const int n = n0 + wc * 64 + ni * 16 + lr;
#pragma unroll
            for (int r = 0; r < 4; ++r) {
                const int m = m0 + wr * 64 + mi * 16 + lk * 4 + r;
                const float v = acc[mi][ni][r];
                if (MODE == 0)
                    ((bf16_t*)Cv)[(size_t)m * ldc + n] = f2bf(v);
                else
                    ((float*)Cv)[(size_t)m * ldc + n] = v > 0.f ? v : expm1f(v);
            }
        }
    }
}

// =====================================================================
// Attr GRU step (R6-validated): 64-row block, h staged once; j-loop 5x64,
// K-loop 10x32; gates = h @ Whh3^T; epilogue gathers xp from proj table.
// =====================================================================
__global__ __launch_bounds__(256)
void gru_attr_step(const bf16_t* __restrict__ hin,
                   bf16_t* __restrict__ hout,
                   const bf16_t* __restrict__ Whh3,   // [960][320]
                   const bf16_t* __restrict__ proj,   // [VP][1024]
                   const int* __restrict__ tokens,
                   const int* __restrict__ lengths,
                   const float* __restrict__ bih, const float* __restrict__ bhh,
                   int T, int t)
{
    constexpr int ASTR = 328;                 // row stride: 656B -> bank offset 4/row
    __shared__ bf16_t As[64 * ASTR];          // 41 KB
    __shared__ bf16_t Bs[3 * 64 * 32];        // 12 KB
    __shared__ int tokL[64], lenL[64];

    const int tid = threadIdx.x;
    const int w = tid >> 6, lane = tid & 63;
    const int lr = lane & 15, lk = lane >> 4;
    const int m0 = blockIdx.x * 64;

    if (tid < 64) {
        tokL[tid] = tokens[(size_t)(m0 + tid) * T + t];
        lenL[tid] = lengths[m0 + tid];
    }

    // stage h tile once: 64 rows x 320 cols (2560 x 16B)
#pragma unroll
    for (int it = 0; it < 10; ++it) {
        const int i = tid + 256 * it;
        const int row = i / 40, c8 = (i - row * 40) * 8;
        const uint4 v = *(const uint4*)(hin + (size_t)(m0 + row) * KPAD + c8);
        *(uint4*)&As[row * ASTR + c8] = v;
    }
    __syncthreads();

    for (int jt = 0; jt < 5; ++jt) {
        const int j0 = jt * 64;
        f32x4_t acc[3][4];
#pragma unroll
        for (int g = 0; g < 3; ++g)
#pragma unroll
            for (int ni = 0; ni < 4; ++ni) acc[g][ni] = {0.f, 0.f, 0.f, 0.f};

        for (int k0 = 0; k0 < KPAD; k0 += 32) {
            // stage Bs: 3 gates x 64 rows x 32 K = 768 x 16B, 3 per thread
            uint4 bv[3];
#pragma unroll
            for (int rp = 0; rp < 3; ++rp) {
                const int i = tid + 256 * rp;
                const int g = i >> 8, q = i & 255;
                const int rr_ = q >> 2, c8 = (q & 3) * 8;
                bv[rp] = *(const uint4*)(Whh3 + (size_t)(g * KPAD + j0 + rr_) * KPAD + k0 + c8);
            }
            __syncthreads();   // prior ds_reads of Bs done
#pragma unroll
            for (int rp = 0; rp < 3; ++rp) {
                const int i = tid + 256 * rp;
                const int g = i >> 8, q = i & 255;
                const int rr_ = q >> 2, c8 = (q & 3) * 8;
                *(uint4*)&Bs[(g * 64 + rr_) * 32 + c8] = bv[rp];
            }
            __syncthreads();

            const bf16x8_t af = *(const bf16x8_t*)&As[(w * 16 + lr) * ASTR + k0 + lk * 8];
#pragma unroll
            for (int g = 0; g < 3; ++g)
#pragma unroll
                for (int ni = 0; ni < 4; ++ni) {
                    const bf16x8_t bfr =
                        *(const bf16x8_t*)&Bs[(g * 64 + ni * 16 + lr) * 32 + lk * 8];
                    acc[g][ni] = __builtin_amdgcn_mfma_f32_16x16x32_bf16(
                        af, bfr, acc[g][ni], 0, 0, 0);
                }
        }

        // epilogue for this j-tile
#pragma unroll
        for (int r = 0; r < 4; ++r) {
            const int ml = w * 16 + lk * 4 + r;
            const int m = m0 + ml;
            const int tok = tokL[ml];
            int len = lenL[ml]; if (len < 1) len = 1;
            const bool act = (t < len);
            const size_t pb = (size_t)tok * PROJW;
#pragma unroll
            for (int ni = 0; ni < 4; ++ni) {
                const int j = j0 + ni * 16 + lr;
                if (j >= WDIM) continue;
                const float hold = bf2f(As[ml * ASTR + j]);
                float hv = hold;
                if (act) {
                    const float xr = bf2f(proj[pb + j]);
                    const float xz = bf2f(proj[pb + KPAD + j]);
                    const float xn = bf2f(proj[pb + 2 * KPAD + j]);
                    const float rr = 1.f / (1.f + expf(-(acc[0][ni][r] + xr + bih[j] + bhh[j])));
                    const float zz = 1.f / (1.f + expf(-(acc[1][ni][r] + xz + bih[WDIM + j] + bhh[WDIM + j])));
                    const float nn = tanhf(xn + bih[2 * WDIM + j] + rr * (acc[2][ni][r] + bhh[2 * WDIM + j]));
                    hv = (1.f - zz) * nn + zz * hold;
                }
                hout[(size_t)m * KPAD + j] = f2bf(hv);
            }
        }
    }
}

// =====================================================================
// Persistent ent GRU (R11): all T steps in one launch; h in LDS.
// R10 (256 thr = 1 wave/SIMD) was latency-bound: Occupancy 11.3%,
// MfmaUtil 3.9%, every L2/LDS/transcendental latency exposed.
// R11: 1024 thr = 16 waves = 4 waves/SIMD, two-phase step:
//   Phase 1: 60 gate-tiles (3g x 20jt, 16x16, K=320) spread 4/wave, B read
//            direct from L2, 4 independent depth-10 MFMA chains/wave;
//            partials -> LDS gates[16][962] (stride 962 = 2 mod 32: 2-way
//            banked = free). xp for t+1 prefetched into regs BEFORE the
//            k-loop, written to double-buffered xp LDS after (T14 split).
//   Phase 2: all 1024 threads split the 16x300 gate epilogue (5 elem/thr).
// Tiles 60..63 clamp to dead tile 59 (jt=19 >= WDIM): identical-value
// duplicate LDS writes, benign. 2 barriers/step. LDS 149.2 KiB, 1 blk/CU.
// =====================================================================
__global__ __launch_bounds__(1024, 1)
void gru_ent_all(bf16_t* __restrict__ hout,        // [G][KPAD]
                 const bf16_t* __restrict__ Whh3,  // [960][320]
                 const bf16_t* __restrict__ proj,  // [VP][1024]
                 const int* __restrict__ tokens,   // [G*T]
                 const int* __restrict__ lengths,  // [G]
                 const float* __restrict__ bih, const float* __restrict__ bhh,
                 int T)
{
    constexpr int HSTR  = 328;
    constexpr int XPSTR = 968;               // 960 used cols + 8 pad
    constexpr int GSTR  = 962;               // f32 stride; 962%32=2 -> 2-way banks
    __shared__ __align__(16) bf16_t hs[2 * 16 * HSTR];   // 20.5 KB (double buffer)
    __shared__ __align__(16) bf16_t xp[2 * 16 * XPSTR];  // 60.5 KB (double buffer)
    __shared__ float  gates[16 * GSTR];                  // 60.1 KB
    __shared__ float  bihL[960], bhhL[960];              // 7.5 KB
    __shared__ int tokL[16 * 8];
    __shared__ int lenL[16];

    const int tid = threadIdx.x;
    const int w = tid >> 6, lane = tid & 63;
    const int lr = lane & 15, lk = lane >> 4;
    const int m0 = blockIdx.x * 16;

    if (tid < 16) lenL[tid] = lengths[m0 + tid];
    if (tid < 16 * T) tokL[tid] = tokens[(size_t)(m0 + (tid & 15)) * T + (tid >> 4)];
    for (int i = tid; i < 900; i += 1024) { bihL[i] = bih[i]; bhhL[i] = bhh[i]; }
    for (int i = tid; i < 2 * 16 * HSTR; i += 1024) hs[i] = 0;   // h0 = 0, pads 0
    __syncthreads();   // tokL visible before xp staging

    // stage xp for t=0 into buffer 0
    for (int i = tid; i < 16 * 120; i += 1024) {
        const int row = i / 120, c8 = (i - row * 120) * 8;
        const size_t pb = (size_t)tokL[row] * PROJW;
        const u32x4 v = __builtin_nontemporal_load((const u32x4*)(proj + pb + c8));
        *(u32x4*)&xp[row * XPSTR + c8] = v;
    }
    // (xp[0] writes drained by the gates barrier inside step 0)

    // per-wave tile assignment: tt = w + 16*i, clamped to 59
    int goA[4];
    const bf16_t* bpA[4];
#pragma unroll
    for (int i = 0; i < 4; ++i) {
        int tt = w + 16 * i; if (tt > 59) tt = 59;
        const int g = tt / 20, jt = tt - g * 20;
        goA[i] = g * KPAD + jt * 16 + lr;   // Whh3 row == gates column (KPAD==320)
        bpA[i] = Whh3 + (size_t)goA[i] * KPAD + lk * 8;
    }

    for (int t = 0; t < T; ++t) {
        const int co = (t & 1) * (16 * HSTR);        // current (read) buffer
        const int no = (16 * HSTR) - co;             // next (write) buffer

        // ---- phase 1: issue next-step xp gather into regs (T14 split) ----
        u32x4 xv0 = {0, 0, 0, 0}, xv1 = {0, 0, 0, 0};
        int xw0 = -1, xw1 = -1;
        if (t + 1 < T) {
            const int xn = ((t + 1) & 1) * (16 * XPSTR);
            {
                const int i = tid;                   // i < 1920 always (tid<1024)
                const int row = i / 120, c8 = (i - row * 120) * 8;
                const size_t pb = (size_t)tokL[(t + 1) * 16 + row] * PROJW;
                xv0 = __builtin_nontemporal_load((const u32x4*)(proj + pb + c8));
                xw0 = xn + row * XPSTR + c8;
            }
            if (tid + 1024 < 16 * 120) {
                const int i = tid + 1024;
                const int row = i / 120, c8 = (i - row * 120) * 8;
                const size_t pb = (size_t)tokL[(t + 1) * 16 + row] * PROJW;
                xv1 = __builtin_nontemporal_load((const u32x4*)(proj + pb + c8));
                xw1 = xn + row * XPSTR + c8;
            }
        }

        // ---- phase 1: gates GEMM, 4 independent chains per wave ----
        f32x4_t a0 = {0.f, 0.f, 0.f, 0.f}, a1 = a0, a2 = a0, a3 = a0;
#pragma unroll 2
        for (int k0 = 0; k0 < KPAD; k0 += 32) {
            const bf16x8_t af = *(const bf16x8_t*)&hs[co + lr * HSTR + k0 + lk * 8];
            a0 = __builtin_amdgcn_mfma_f32_16x16x32_bf16(af, *(const bf16x8_t*)(bpA[0] + k0), a0, 0, 0, 0);
            a1 = __builtin_amdgcn_mfma_f32_16x16x32_bf16(af, *(const bf16x8_t*)(bpA[1] + k0), a1, 0, 0, 0);
            a2 = __builtin_amdgcn_mfma_f32_16x16x32_bf16(af, *(const bf16x8_t*)(bpA[2] + k0), a2, 0, 0, 0);
            a3 = __builtin_amdgcn_mfma_f32_16x16x32_bf16(af, *(const bf16x8_t*)(bpA[3] + k0), a3, 0, 0, 0);
        }

        // late xp LDS write (loads have drained under the GEMM)
        if (xw0 >= 0) *(u32x4*)&xp[xw0] = xv0;
        if (xw1 >= 0) *(u32x4*)&xp[xw1] = xv1;

        // scatter partials to gates LDS
#pragma unroll
        for (int r = 0; r < 4; ++r) {
            const int mrow = lk * 4 + r;
            gates[mrow * GSTR + goA[0]] = a0[r];
            gates[mrow * GSTR + goA[1]] = a1[r];
            gates[mrow * GSTR + goA[2]] = a2[r];
            gates[mrow * GSTR + goA[3]] = a3[r];
        }
        __syncthreads();   // gates + xp[t+1] visible

        // ---- phase 2: epilogue, 5 elements per thread ----
        const int xo = (t & 1) * (16 * XPSTR);
#pragma unroll
        for (int i = 0; i < 5; ++i) {
            const int e = tid + 1024 * i;
            const int m = e / 320, j = e - m * 320;
            if (j < WDIM) {
                const float hold = bf2f(hs[co + m * HSTR + j]);
                float hv = hold;
                int len = lenL[m]; if (len < 1) len = 1;
                if (t < len) {
                    const float xr  = bf2f(xp[xo + m * XPSTR + j]);
                    const float xz  = bf2f(xp[xo + m * XPSTR + KPAD + j]);
                    const float xnn = bf2f(xp[xo + m * XPSTR + 2 * KPAD + j]);
                    const float g0 = gates[m * GSTR + j];
                    const float g1 = gates[m * GSTR + KPAD + j];
                    const float g2 = gates[m * GSTR + 2 * KPAD + j];
                    const float rr = 1.f / (1.f + expf(-(g0 + xr + bihL[j] + bhhL[j])));
                    const float zz = 1.f / (1.f + expf(-(g1 + xz + bihL[WDIM + j] + bhhL[WDIM + j])));
                    const float nn = tanhf(xnn + bihL[2 * WDIM + j] +
                                           rr * (g2 + bhhL[2 * WDIM + j]));
                    hv = (1.f - zz) * nn + zz * hold;
                }
                hs[no + m * HSTR + j] = f2bf(hv);
            }
        }
        __syncthreads();   // hs[no]/gates/xp reads done before next step
    }

    // final state is in buffer (T & 1)
    const int fo = (T & 1) * (16 * HSTR);
    for (int i = tid; i < 16 * 40; i += 1024) {
        const int row = i / 40, c8 = (i - row * 40) * 8;
        *(uint4*)&hout[(size_t)(m0 + row) * KPAD + c8] = *(const uint4*)&hs[fo + row * HSTR + c8];
    }
}

// =====================================================================
// FC + relu -> nodes (bf16) with FUSED es/ed (R6-validated).
// =====================================================================
__global__ __launch_bounds__(256)
void fc_nodes_esed(const bf16_t* __restrict__ hEnt, const bf16_t* __restrict__ hAtt,
                   const bf16_t* __restrict__ WfcB, const float* __restrict__ bfc,
                   const float* __restrict__ asW, const float* __restrict__ adW,
                   bf16_t* __restrict__ nodes, float* __restrict__ es, float* __restrict__ ed)
{
    constexpr int ASTR = 328;
    __shared__ bf16_t As[64 * ASTR];          // 41 KB
    __shared__ bf16_t Bs[64 * 32];            // 4 KB
    __shared__ const bf16_t* rowp[64];

    const int tid = threadIdx.x;
    const int w = tid >> 6, lane = tid & 63;
    const int lr = lane & 15, lk = lane >> 4;
    const int m0 = blockIdx.x * 64;

    if (tid < 64) {
        const int m = m0 + tid;
        const int g = m / NNODE, i = m - g * NNODE;
        rowp[tid] = (i == 0) ? (hEnt + (size_t)g * KPAD)
                             : (hAtt + (size_t)(g * 8 + (i - 1)) * KPAD);
    }
    __syncthreads();

#pragma unroll
    for (int it = 0; it < 10; ++it) {
        const int i = tid + 256 * it;
        const int row = i / 40, c8 = (i - row * 40) * 8;
        const uint4 v = *(const uint4*)(rowp[row] + c8);
        *(uint4*)&As[row * ASTR + c8] = v;
    }
    __syncthreads();

    float esa[4] = {0.f, 0.f, 0.f, 0.f};
    float eda[4] = {0.f, 0.f, 0.f, 0.f};

    for (int nt = 0; nt < 16; ++nt) {
        const int n0 = nt * 64;
        f32x4_t acc[4];
#pragma unroll
        for (int ni = 0; ni < 4; ++ni) acc[ni] = {0.f, 0.f, 0.f, 0.f};

        for (int k0 = 0; k0 < KPAD; k0 += 32) {
            const int rr_ = tid >> 2, c8 = (tid & 3) * 8;
            const uint4 bv = *(const uint4*)(WfcB + (size_t)(n0 + rr_) * KPAD + k0 + c8);
            __syncthreads();
            *(uint4*)&Bs[rr_ * 32 + c8] = bv;
            __syncthreads();

            const bf16x8_t af = *(const bf16x8_t*)&As[(w * 16 + lr) * ASTR + k0 + lk * 8];
#pragma unroll
            for (int ni = 0; ni < 4; ++ni) {
                const bf16x8_t bfr = *(const bf16x8_t*)&Bs[(ni * 16 + lr) * 32 + lk * 8];
                acc[ni] = __builtin_amdgcn_mfma_f32_16x16x32_bf16(af, bfr, acc[ni], 0, 0, 0);
            }
        }

#pragma unroll
        for (int ni = 0; ni < 4; ++ni) {
            const int n = n0 + ni * 16 + lr;
            const float aw = asW[n], dw = adW[n], bb = bfc[n];
#pragma unroll
            for (int r = 0; r < 4; ++r) {
                float v = acc[ni][r] + bb;
                v = v > 0.f ? v : 0.f;
                const int m = m0 + w * 16 + lk * 4 + r;
                nodes[(size_t)m * HDIM + n] = f2bf(v);
                esa[r] = fmaf(v, aw, esa[r]);
                eda[r] = fmaf(v, dw, eda[r]);
            }
        }
    }

    // reduce across the 16 lr lanes
#pragma unroll
    for (int r = 0; r < 4; ++r) {
        float s = esa[r], d = eda[r];
#pragma unroll
        for (int mask = 1; mask < 16; mask <<= 1) {
            s += __shfl_xor(s, mask, 64);
            d += __shfl_xor(d, mask, 64);
        }
        if (lr == 0) {
            const int m = m0 + w * 16 + lk * 4 + r;
            es[m] = s; ed[m] = d;
        }
    }
}

// =====================================================================
// Prep kernels
// =====================================================================
__global__ __launch_bounds__(256)
void convert_emb_kernel(const float* __restrict__ emb, bf16_t* __restrict__ embB)
{
    const int idx = blockIdx.x * 256 + threadIdx.x;    // over V_*40
    if (idx >= V_ * 40) return;
    const int row = idx / 40, c8 = (idx - row * 40) * 8;
    bf16_t o[8];
#pragma unroll
    for (int e = 0; e < 8; ++e) {
        const int c = c8 + e;
        o[e] = (c < WDIM) ? f2bf(emb[(size_t)row * WDIM + c]) : (bf16_t)0;
    }
    *(ushort4*)(embB + (size_t)row * KPAD + c8)     = *(ushort4*)&o[0];
    *(ushort4*)(embB + (size_t)row * KPAD + c8 + 4) = *(ushort4*)&o[4];
}

// W [3*300][300] fp32 -> [nrows][320] bf16 rows n=g*320+j (zero-padded)
__global__ __launch_bounds__(256)
void build_w3_kernel(const float* __restrict__ W, bf16_t* __restrict__ dst, int nrows)
{
    const int idx = blockIdx.x * 256 + threadIdx.x;
    if (idx >= nrows * KPAD) return;
    const int n = idx / KPAD, k = idx - n * KPAD;
    const int g = n / KPAD, j = n - g * KPAD;
    float v = 0.f;
    if (g < 3 && j < WDIM && k < WDIM)
        v = W[(size_t)(g * WDIM + j) * WDIM + k];
    dst[idx] = f2bf(v);
}

__global__ __launch_bounds__(256)
void build_wfc_kernel(const float* __restrict__ Wfc, bf16_t* __restrict__ Wb)
{
    const int idx = blockIdx.x * 256 + threadIdx.x;    // over 1024*320
    if (idx >= HDIM * KPAD) return;
    const int n = idx / KPAD, k = idx - n * KPAD;
    Wb[idx] = f2bf(k < WDIM ? Wfc[(size_t)n * WDIM + k] : 0.f);
}

__global__ __launch_bounds__(256)
void build_wg_kernel(const float* __restrict__ Wg, bf16_t* __restrict__ Wb)
{
    const int idx = blockIdx.x * 256 + threadIdx.x;    // over 1024*1024
    Wb[idx] = f2bf(Wg[idx]);
}

// asW = a_src @ Wg, adW = a_dst @ Wg
__global__ __launch_bounds__(256)
void asw_kernel(const float* __restrict__ Wg,
                const float* __restrict__ a_src, const float* __restrict__ a_dst,
                float* __restrict__ asW, float* __restrict__ adW)
{
    const int k = blockIdx.x * 256 + threadIdx.x;
    float s = 0.f, d = 0.f;
    for (int n = 0; n < HDIM; ++n) {
        const float w = Wg[(size_t)n * HDIM + k];
        s = fmaf(a_src[n], w, s);
        d = fmaf(a_dst[n], w, d);
    }
    asW[k] = s; adW[k] = d;
}

// Row-0 star attention -> mixed[g] = sum_j alpha_j * nodes[g*9+j] (bf16)
__global__ __launch_bounds__(256)
void attn_mix_kernel(const bf16_t* __restrict__ nodes,
                     const float* __restrict__ es, const float* __restrict__ ed,
                     bf16_t* __restrict__ mixed)
{
    const int g = blockIdx.x;
    const float e0 = es[(size_t)g * NNODE];
    const float* edg = ed + (size_t)g * NNODE;

    float w[NNODE], mx = -1e30f;
#pragma unroll
    for (int j = 0; j < NNODE; ++j) {
        float v = e0 + edg[j];
        v = v >= 0.f ? v : 0.2f * v;
        w[j] = v; mx = fmaxf(mx, v);
    }
    float denom = 0.f;
#pragma unroll
    for (int j = 0; j < NNODE; ++j) { w[j] = expf(w[j] - mx); denom += w[j]; }
    const float inv = 1.f / denom;

    const int c = threadIdx.x * 4;
    float4 acc = {0.f, 0.f, 0.f, 0.f};
#pragma unroll
    for (int j = 0; j < NNODE; ++j) {
        const float a = w[j] * inv;
        const ushort4 h4 = *(const ushort4*)(nodes + (size_t)(g * NNODE + j) * HDIM + c);
        acc.x = fmaf(a, bf2f(h4.x), acc.x);
        acc.y = fmaf(a, bf2f(h4.y), acc.y);
        acc.z = fmaf(a, bf2f(h4.z), acc.z);
        acc.w = fmaf(a, bf2f(h4.w), acc.w);
    }
    ushort4 o;
    o.x = f2bf(acc.x); o.y = f2bf(acc.y); o.z = f2bf(acc.z); o.w = f2bf(acc.w);
    *(ushort4*)(mixed + (size_t)g * HDIM + c) = o;
}

// -------- workspace layout (~131 MiB; 157 MiB known-safe) --------
constexpr size_t SZ_EMBB  = (size_t)VP * KPAD * sizeof(bf16_t);      // 19.58 MB
constexpr size_t SZ_PROJ  = (size_t)VP * PROJW * sizeof(bf16_t);     // 62.65 MB
constexpr size_t SZ_HATT  = (size_t)GA * KPAD * sizeof(bf16_t);      // 20.97 MB x2
constexpr size_t SZ_HENT  = (size_t)G * KPAD * sizeof(bf16_t);       //  2.62 MB
constexpr size_t SZ_WIH3  = (size_t)HDIM * KPAD * sizeof(bf16_t);
constexpr size_t SZ_WHH3  = (size_t)960 * KPAD * sizeof(bf16_t);     //  0.61 MB x2
constexpr size_t SZ_WFC   = (size_t)HDIM * KPAD * sizeof(bf16_t);
constexpr size_t SZ_WG    = (size_t)HDIM * HDIM * sizeof(bf16_t);
constexpr size_t SZ_AW    = (size_t)HDIM * sizeof(float);
constexpr size_t SZ_VEC   = (size_t)MROWS * sizeof(float);
constexpr size_t SZ_NODE  = (size_t)MROWS * HDIM * sizeof(bf16_t);   // 75.5 MB
constexpr size_t SZ_MIX   = (size_t)G * HDIM * sizeof(bf16_t);
constexpr size_t WS_NEED  = SZ_EMBB + SZ_PROJ + 2 * SZ_HATT + SZ_HENT +
                            SZ_WIH3 + 2 * SZ_WHH3 + SZ_WFC + SZ_WG +
                            2 * SZ_AW + 2 * SZ_VEC;
static_assert(SZ_NODE <= SZ_EMBB + SZ_PROJ, "nodes overlays embB+proj");
static_assert(SZ_MIX  <= 2 * SZ_HATT,       "mixed overlays hAtt pair");

} // namespace

extern "C" void kernel_launch(void* const* d_in, const int* in_sizes, int n_in,
                              void* d_out, int out_size, void* d_ws, size_t ws_size,
                              hipStream_t stream)
{
    (void)in_sizes; (void)n_in; (void)out_size;
    if (ws_size < WS_NEED) return;   // clean absmax failure instead of fault

    const int*   ent_tok  = (const int*)  d_in[0];
    const int*   ent_len  = (const int*)  d_in[1];
    const int*   at_tok   = (const int*)  d_in[3];
    const int*   at_len   = (const int*)  d_in[4];
    const float* emb      = (const float*)d_in[6];
    const float* Wih_ent  = (const float*)d_in[7];
    const float* Whh_ent  = (const float*)d_in[8];
    const float* bih_ent  = (const float*)d_in[9];
    const float* bhh_ent  = (const float*)d_in[10];
    const float* Wih_attr = (const float*)d_in[11];
    const float* Whh_attr = (const float*)d_in[12];
    const float* bih_attr = (const float*)d_in[13];
    const float* bhh_attr = (const float*)d_in[14];
    const float* Wfc      = (const float*)d_in[15];
    const float* bfc      = (const float*)d_in[16];
    const float* Wg       = (const float*)d_in[17];
    const float* a_src    = (const float*)d_in[18];
    const float* a_dst    = (const float*)d_in[19];
    float* out = (float*)d_out;

    char* p = (char*)d_ws;
    bf16_t* embB  = (bf16_t*)p; p += SZ_EMBB;
    bf16_t* proj  = (bf16_t*)p; p += SZ_PROJ;
    bf16_t* hAtt[2];
    hAtt[0] = (bf16_t*)p; p += SZ_HATT;
    hAtt[1] = (bf16_t*)p; p += SZ_HATT;
    bf16_t* hEnt   = (bf16_t*)p; p += SZ_HENT;
    bf16_t* Wih3   = (bf16_t*)p; p += SZ_WIH3;
    bf16_t* Whh3_a = (bf16_t*)p; p += SZ_WHH3;
    bf16_t* Whh3_e = (bf16_t*)p; p += SZ_WHH3;
    bf16_t* WfcB   = (bf16_t*)p; p += SZ_WFC;
    bf16_t* WgB    = (bf16_t*)p; p += SZ_WG;
    float*  asW    = (float*)p;  p += SZ_AW;
    float*  adW    = (float*)p;  p += SZ_AW;
    float*  es     = (float*)p;  p += SZ_VEC;
    float*  ed     = (float*)p;  p += SZ_VEC;
    bf16_t* nodes  = embB;       // overlay: embB+proj dead after GRU loops
    bf16_t* mixed  = hAtt[0];    // overlay: hAtt dead after fc_nodes_esed

    // zero attr h ping-pong buffers (h0 = 0; pad cols must stay 0)
    hipMemsetAsync(hAtt[0], 0, SZ_HATT, stream);
    hipMemsetAsync(hAtt[1], 0, SZ_HATT, stream);

    // prep
    convert_emb_kernel<<<dim3((V_ * 40 + 255) / 256), 256, 0, stream>>>(emb, embB);
    build_w3_kernel<<<dim3(HDIM * KPAD / 256), 256, 0, stream>>>(Wih_attr, Wih3, HDIM);
    build_w3_kernel<<<dim3(960 * KPAD / 256), 256, 0, stream>>>(Whh_attr, Whh3_a, 960);
    build_w3_kernel<<<dim3(960 * KPAD / 256), 256, 0, stream>>>(Whh_ent, Whh3_e, 960);
    build_wfc_kernel<<<dim3(HDIM * KPAD / 256), 256, 0, stream>>>(Wfc, WfcB);
    build_wg_kernel<<<dim3(HDIM * HDIM / 256), 256, 0, stream>>>(Wg, WgB);
    asw_kernel<<<dim3(HDIM / 256), 256, 0, stream>>>(Wg, a_src, a_dst, asW, adW);

    // attr vocab projection: proj[v] = embB[v] @ Wih3_attr^T
    mfma_gemm<0><<<dim3(VP / 128, PROJW / 128), 256, 0, stream>>>(
        embB, Wih3, proj, KPAD, KPAD, PROJW, KPAD);

    // attr GRU: T=4 (final h in hAtt[0])
    for (int t = 0; t < TA_; ++t)
        gru_attr_step<<<dim3(GA / 64), 256, 0, stream>>>(
            hAtt[t & 1], hAtt[(t + 1) & 1], Whh3_a, proj, at_tok, at_len,
            bih_attr, bhh_attr, TA_, t);

    // ent vocab projection (rebuild Wih3 with Wih_ent; overwrite proj)
    build_w3_kernel<<<dim3(HDIM * KPAD / 256), 256, 0, stream>>>(Wih_ent, Wih3, HDIM);
    mfma_gemm<0><<<dim3(VP / 128, PROJW / 128), 256, 0, stream>>>(
        embB, Wih3, proj, KPAD, KPAD, PROJW, KPAD);

    // ent GRU: all T=8 steps in ONE persistent launch (h in LDS), 16 waves/CU
    gru_ent_all<<<dim3(G / 16), 1024, 0, stream>>>(
        hEnt, Whh3_e, proj, ent_tok, ent_len, bih_ent, bhh_ent, TE_);

    // nodes = relu(h @ Wfc^T + bfc) with fused es/ed
    fc_nodes_esed<<<dim3(MROWS / 64), 256, 0, stream>>>(
        hEnt, hAtt[0], WfcB, bfc, asW, adW, nodes, es, ed);

    // row-0 softmax + node mixing
    attn_mix_kernel<<<dim3(G), 256, 0, stream>>>(nodes, es, ed, mixed);

    // out = elu(mixed @ Wg^T)
    mfma_gemm<2><<<dim3(G / 128, HDIM / 128), 256, 0, stream>>>(
        mixed, WgB, out, HDIM, HDIM, HDIM, HDIM);
}

// Round 3
// 845.629 us; speedup vs baseline: 1.1643x; 1.0870x over previous
//
#include <hip/hip_runtime.h>
#include <math.h>

namespace {

typedef unsigned short bf16_t;
typedef __bf16  bf16x8_t __attribute__((ext_vector_type(8)));
typedef float   f32x4_t  __attribute__((ext_vector_type(4)));
typedef unsigned int u32x4 __attribute__((ext_vector_type(4)));

constexpr int G     = 4096;      // BS*E
constexpr int GA    = 32768;     // G*A
constexpr int WDIM  = 300;
constexpr int KPAD  = 320;
constexpr int HDIM  = 1024;
constexpr int NNODE = 9;
constexpr int MROWS = G * NNODE; // 36864
constexpr int TE_   = 8;
constexpr int TA_   = 4;
constexpr int V_    = 30522;
constexpr int VP    = 30592;     // 239*128
constexpr int PROJW = 1024;

__device__ __forceinline__ float bf2f(bf16_t b) {
    union { unsigned int u; float f; } v; v.u = ((unsigned int)b) << 16; return v.f;
}
__device__ __forceinline__ bf16_t f2bf(float f) {
    union { float f; unsigned int u; } v; v.f = f;
    unsigned int r = v.u + 0x7FFFu + ((v.u >> 16) & 1u);   // RNE
    return (bf16_t)(r >> 16);
}

// =====================================================================
// Generic 128x128-tile bf16 MFMA GEMM (validated R3/R4): C = A[M,K] @ B[N,K]^T
// MODE 0: C bf16 (vocab projection)   MODE 2: C fp32 with elu (final out)
// =====================================================================
template<int MODE>
__global__ __launch_bounds__(256)
void mfma_gemm(const bf16_t* __restrict__ A, const bf16_t* __restrict__ B,
               void* __restrict__ Cv, int lda, int ldb, int ldc, int K)
{
    __shared__ bf16_t As[128 * 32];
    __shared__ bf16_t Bs[128 * 32];

    const int tid  = threadIdx.x;
    const int w    = tid >> 6;
    const int lane = tid & 63;
    const int wr = w >> 1, wc = w & 1;
    const int lr = lane & 15;
    const int lk = lane >> 4;
    const int m0 = blockIdx.x * 128, n0 = blockIdx.y * 128;

    const int r0 = tid >> 2;
    const int cc = (tid & 3) * 8;
    const bf16_t* Arow0 = A + (size_t)(m0 + r0) * lda + cc;
    const bf16_t* Arow1 = Arow0 + (size_t)64 * lda;
    const bf16_t* Brow0 = B + (size_t)(n0 + r0) * ldb + cc;
    const bf16_t* Brow1 = Brow0 + (size_t)64 * ldb;

    f32x4_t acc[4][4];
#pragma unroll
    for (int i = 0; i < 4; ++i)
#pragma unroll
        for (int j = 0; j < 4; ++j) acc[i][j] = {0.f, 0.f, 0.f, 0.f};

    for (int k0 = 0; k0 < K; k0 += 32) {
        const uint4 a0 = *(const uint4*)(Arow0 + k0);
        const uint4 a1 = *(const uint4*)(Arow1 + k0);
        const uint4 b0 = *(const uint4*)(Brow0 + k0);
        const uint4 b1 = *(const uint4*)(Brow1 + k0);
        __syncthreads();
        *(uint4*)&As[r0 * 32 + cc]        = a0;
        *(uint4*)&As[(r0 + 64) * 32 + cc] = a1;
        *(uint4*)&Bs[r0 * 32 + cc]        = b0;
        *(uint4*)&Bs[(r0 + 64) * 32 + cc] = b1;
        __syncthreads();

        bf16x8_t af[4], bfr[4];
#pragma unroll
        for (int i = 0; i < 4; ++i) {
            af[i]  = *(const bf16x8_t*)&As[(wr * 64 + i * 16 + lr) * 32 + lk * 8];
            bfr[i] = *(const bf16x8_t*)&Bs[(wc * 64 + i * 16 + lr) * 32 + lk * 8];
        }
#pragma unroll
        for (int mi = 0; mi < 4; ++mi)
#pragma unroll
            for (int ni = 0; ni < 4; ++ni)
                acc[mi][ni] = __builtin_amdgcn_mfma_f32_16x16x32_bf16(
                    af[mi], bfr[ni], acc[mi][ni], 0, 0, 0);
    }

#pragma unroll
    for (int mi = 0; mi < 4; ++mi) {
#pragma unroll
        for (int ni = 0; ni < 4; ++ni) {
            const int n = n0 + wc * 64 + ni * 16 + lr;
#pragma unroll
            for (int r = 0; r < 4; ++r) {
                const int m = m0 + wr * 64 + mi * 16 + lk * 4 + r;
                const float v = acc[mi][ni][r];
                if (MODE == 0)
                    ((bf16_t*)Cv)[(size_t)m * ldc + n] = f2bf(v);
                else
                    ((float*)Cv)[(size_t)m * ldc + n] = v > 0.f ? v : expm1f(v);
            }
        }
    }
}

// =====================================================================
// Attr GRU step (R6-validated): 64-row block, h staged once; j-loop 5x64,
// K-loop 10x32; gates = h @ Whh3^T; epilogue gathers xp from proj table.
// =====================================================================
__global__ __launch_bounds__(256)
void gru_attr_step(const bf16_t* __restrict__ hin,
                   bf16_t* __restrict__ hout,
                   const bf16_t* __restrict__ Whh3,   // [960][320]
                   const bf16_t* __restrict__ proj,   // [VP][1024]
                   const int* __restrict__ tokens,
                   const int* __restrict__ lengths,
                   const float* __restrict__ bih, const float* __restrict__ bhh,
                   int T, int t)
{
    constexpr int ASTR = 328;                 // row stride: 656B -> bank offset 4/row
    __shared__ bf16_t As[64 * ASTR];          // 41 KB
    __shared__ bf16_t Bs[3 * 64 * 32];        // 12 KB
    __shared__ int tokL[64], lenL[64];

    const int tid = threadIdx.x;
    const int w = tid >> 6, lane = tid & 63;
    const int lr = lane & 15, lk = lane >> 4;
    const int m0 = blockIdx.x * 64;

    if (tid < 64) {
        tokL[tid] = tokens[(size_t)(m0 + tid) * T + t];
        lenL[tid] = lengths[m0 + tid];
    }

    // stage h tile once: 64 rows x 320 cols (2560 x 16B)
#pragma unroll
    for (int it = 0; it < 10; ++it) {
        const int i = tid + 256 * it;
        const int row = i / 40, c8 = (i - row * 40) * 8;
        const uint4 v = *(const uint4*)(hin + (size_t)(m0 + row) * KPAD + c8);
        *(uint4*)&As[row * ASTR + c8] = v;
    }
    __syncthreads();

    for (int jt = 0; jt < 5; ++jt) {
        const int j0 = jt * 64;
        f32x4_t acc[3][4];
#pragma unroll
        for (int g = 0; g < 3; ++g)
#pragma unroll
            for (int ni = 0; ni < 4; ++ni) acc[g][ni] = {0.f, 0.f, 0.f, 0.f};

        for (int k0 = 0; k0 < KPAD; k0 += 32) {
            // stage Bs: 3 gates x 64 rows x 32 K = 768 x 16B, 3 per thread
            uint4 bv[3];
#pragma unroll
            for (int rp = 0; rp < 3; ++rp) {
                const int i = tid + 256 * rp;
                const int g = i >> 8, q = i & 255;
                const int rr_ = q >> 2, c8 = (q & 3) * 8;
                bv[rp] = *(const uint4*)(Whh3 + (size_t)(g * KPAD + j0 + rr_) * KPAD + k0 + c8);
            }
            __syncthreads();   // prior ds_reads of Bs done
#pragma unroll
            for (int rp = 0; rp < 3; ++rp) {
                const int i = tid + 256 * rp;
                const int g = i >> 8, q = i & 255;
                const int rr_ = q >> 2, c8 = (q & 3) * 8;
                *(uint4*)&Bs[(g * 64 + rr_) * 32 + c8] = bv[rp];
            }
            __syncthreads();

            const bf16x8_t af = *(const bf16x8_t*)&As[(w * 16 + lr) * ASTR + k0 + lk * 8];
#pragma unroll
            for (int g = 0; g < 3; ++g)
#pragma unroll
                for (int ni = 0; ni < 4; ++ni) {
                    const bf16x8_t bfr =
                        *(const bf16x8_t*)&Bs[(g * 64 + ni * 16 + lr) * 32 + lk * 8];
                    acc[g][ni] = __builtin_amdgcn_mfma_f32_16x16x32_bf16(
                        af, bfr, acc[g][ni], 0, 0, 0);
                }
        }

        // epilogue for this j-tile
#pragma unroll
        for (int r = 0; r < 4; ++r) {
            const int ml = w * 16 + lk * 4 + r;
            const int m = m0 + ml;
            const int tok = tokL[ml];
            int len = lenL[ml]; if (len < 1) len = 1;
            const bool act = (t < len);
            const size_t pb = (size_t)tok * PROJW;
#pragma unroll
            for (int ni = 0; ni < 4; ++ni) {
                const int j = j0 + ni * 16 + lr;
                if (j >= WDIM) continue;
                const float hold = bf2f(As[ml * ASTR + j]);
                float hv = hold;
                if (act) {
                    const float xr = bf2f(proj[pb + j]);
                    const float xz = bf2f(proj[pb + KPAD + j]);
                    const float xn = bf2f(proj[pb + 2 * KPAD + j]);
                    const float rr = 1.f / (1.f + expf(-(acc[0][ni][r] + xr + bih[j] + bhh[j])));
                    const float zz = 1.f / (1.f + expf(-(acc[1][ni][r] + xz + bih[WDIM + j] + bhh[WDIM + j])));
                    const float nn = tanhf(xn + bih[2 * WDIM + j] + rr * (acc[2][ni][r] + bhh[2 * WDIM + j]));
                    hv = (1.f - zz) * nn + zz * hold;
                }
                hout[(size_t)m * KPAD + j] = f2bf(hv);
            }
        }
    }
}

// =====================================================================
// Ent GRU step (R13): one launch per step; fused GEMM + gate epilogue.
// gates[4096x960] = h @ Whh3i^T as a PROPER GEMM: tile M=128 x N=120
// (40 j-cols x 3 gates, interleaved n = 3j+g), grid 32x8, 512 thr.
// R12 BUG (nondeterminism + absmax 2.5x): scatter wrote tile cols
// 120..127 (the 8-col B-stage overlap) into gsm with row stride 123,
// aliasing onto gsm[row+1][0..4] — a wave-order LDS race corrupting the
// next row's gates. R13: predicate scatter on col < 120.
// =====================================================================
__global__ __launch_bounds__(512)
void gru_step_fused(const bf16_t* __restrict__ hin,     // [G][KPAD]
                    bf16_t* __restrict__ hout,          // [G][KPAD]
                    const bf16_t* __restrict__ Whh3i,   // [1024][320] n=3j+g
                    const bf16_t* __restrict__ proj,    // [VP][1024]  n=3j+g
                    const int* __restrict__ tokens,
                    const int* __restrict__ lengths,
                    const float* __restrict__ bih, const float* __restrict__ bhh,
                    int T, int t)
{
    constexpr int GSTRF = 123;               // odd f32 stride; 120 used cols
    __shared__ __align__(16) bf16_t As[128 * 32];   // 8 KB
    __shared__ __align__(16) bf16_t Bs[128 * 32];   // 8 KB
    __shared__ float gsm[128 * GSTRF];              // 61.5 KB

    const int tid = threadIdx.x;
    const int w = tid >> 6, lane = tid & 63;
    const int lr = lane & 15, lk = lane >> 4;
    const int wr = w >> 2, wc = w & 3;       // 2 (M) x 4 (N) waves
    const int m0 = blockIdx.x * 128;
    const int nb = blockIdx.y;               // 0..7
    const int n0 = nb * 120;

    const int sr = tid >> 2, sc = (tid & 3) * 8;
    const bf16_t* Ap = hin   + (size_t)(m0 + sr) * KPAD + sc;
    const bf16_t* Bp = Whh3i + (size_t)(n0 + sr) * KPAD + sc;

    f32x4_t acc[4][2];
#pragma unroll
    for (int mi = 0; mi < 4; ++mi)
#pragma unroll
        for (int ni = 0; ni < 2; ++ni) acc[mi][ni] = {0.f, 0.f, 0.f, 0.f};

    for (int k0 = 0; k0 < KPAD; k0 += 32) {
        const uint4 av = *(const uint4*)(Ap + k0);
        const uint4 bv = *(const uint4*)(Bp + k0);
        __syncthreads();
        *(uint4*)&As[sr * 32 + sc] = av;
        *(uint4*)&Bs[sr * 32 + sc] = bv;
        __syncthreads();

        bf16x8_t af[4], bfr[2];
#pragma unroll
        for (int mi = 0; mi < 4; ++mi)
            af[mi] = *(const bf16x8_t*)&As[(wr * 64 + mi * 16 + lr) * 32 + lk * 8];
#pragma unroll
        for (int ni = 0; ni < 2; ++ni)
            bfr[ni] = *(const bf16x8_t*)&Bs[(wc * 32 + ni * 16 + lr) * 32 + lk * 8];
#pragma unroll
        for (int mi = 0; mi < 4; ++mi)
#pragma unroll
            for (int ni = 0; ni < 2; ++ni)
                acc[mi][ni] = __builtin_amdgcn_mfma_f32_16x16x32_bf16(
                    af[mi], bfr[ni], acc[mi][ni], 0, 0, 0);
    }

    // scatter wave tiles to gates LDS (row = M, col = N); cols >= 120 are
    // the B-stage overlap belonging to the next nb block — DO NOT scatter
    // (they'd alias gsm[row+1][0..4] given GSTRF=123: R12's race).
#pragma unroll
    for (int ni = 0; ni < 2; ++ni) {
        const int col = wc * 32 + ni * 16 + lr;
        if (col < 120) {
#pragma unroll
            for (int mi = 0; mi < 4; ++mi)
#pragma unroll
                for (int r = 0; r < 4; ++r)
                    gsm[(wr * 64 + mi * 16 + lk * 4 + r) * GSTRF + col]
                        = acc[mi][ni][r];
        }
    }
    __syncthreads();

    // ---- fused GRU epilogue: thread -> (row ml, quarter q), 10 j each ----
    const int ml = tid >> 2, q = tid & 3;
    if (nb == 7 && q >= 2) return;           // j >= 300 (boundary is exact)
    const int m  = m0 + ml;
    const int jb = nb * 40 + q * 10;
    int len = lengths[m]; if (len < 1) len = 1;
    const bool act = (t < len);
    const int tok = tokens[(size_t)m * T + t];

    const unsigned int* xpp =
        (const unsigned int*)(proj + (size_t)tok * PROJW + n0 + q * 30);
    unsigned int xw[15];
#pragma unroll
    for (int i = 0; i < 15; ++i) xw[i] = xpp[i];

    const unsigned int* hop = (const unsigned int*)(hin + (size_t)m * KPAD + jb);
    unsigned int hw[5];
#pragma unroll
    for (int i = 0; i < 5; ++i) hw[i] = hop[i];

    unsigned int ow[5];
#pragma unroll
    for (int u = 0; u < 10; ++u) {
        const int j = jb + u;
        const bf16_t hob = (bf16_t)((u & 1) ? (hw[u >> 1] >> 16) : (hw[u >> 1] & 0xffff));
        const float hold = bf2f(hob);
        float hv = hold;
        if (act) {
            const int e0 = 3 * u;
            const float xr = bf2f((bf16_t)((e0 & 1)       ? (xw[e0 >> 1] >> 16)       : (xw[e0 >> 1] & 0xffff)));
            const float xz = bf2f((bf16_t)(((e0 + 1) & 1) ? (xw[(e0 + 1) >> 1] >> 16) : (xw[(e0 + 1) >> 1] & 0xffff)));
            const float xn = bf2f((bf16_t)(((e0 + 2) & 1) ? (xw[(e0 + 2) >> 1] >> 16) : (xw[(e0 + 2) >> 1] & 0xffff)));
            const int nl = q * 30 + 3 * u;
            const float g0 = gsm[ml * GSTRF + nl];
            const float g1 = gsm[ml * GSTRF + nl + 1];
            const float g2 = gsm[ml * GSTRF + nl + 2];
            const float rr = 1.f / (1.f + expf(-(g0 + xr + bih[j] + bhh[j])));
            const float zz = 1.f / (1.f + expf(-(g1 + xz + bih[WDIM + j] + bhh[WDIM + j])));
            const float nn = tanhf(xn + bih[2 * WDIM + j] + rr * (g2 + bhh[2 * WDIM + j]));
            hv = (1.f - zz) * nn + zz * hold;
        }
        const bf16_t hb_ = f2bf(hv);
        if ((u & 1) == 0) ow[u >> 1] = hb_;
        else              ow[u >> 1] |= ((unsigned int)hb_) << 16;
    }
    unsigned int* outp = (unsigned int*)(hout + (size_t)m * KPAD + jb);
#pragma unroll
    for (int i = 0; i < 5; ++i) outp[i] = ow[i];
}

// =====================================================================
// FC + relu -> nodes (bf16) with FUSED es/ed (R6-validated).
// =====================================================================
__global__ __launch_bounds__(256)
void fc_nodes_esed(const bf16_t* __restrict__ hEnt, const bf16_t* __restrict__ hAtt,
                   const bf16_t* __restrict__ WfcB, const float* __restrict__ bfc,
                   const float* __restrict__ asW, const float* __restrict__ adW,
                   bf16_t* __restrict__ nodes, float* __restrict__ es, float* __restrict__ ed)
{
    constexpr int ASTR = 328;
    __shared__ bf16_t As[64 * ASTR];          // 41 KB
    __shared__ bf16_t Bs[64 * 32];            // 4 KB
    __shared__ const bf16_t* rowp[64];

    const int tid = threadIdx.x;
    const int w = tid >> 6, lane = tid & 63;
    const int lr = lane & 15, lk = lane >> 4;
    const int m0 = blockIdx.x * 64;

    if (tid < 64) {
        const int m = m0 + tid;
        const int g = m / NNODE, i = m - g * NNODE;
        rowp[tid] = (i == 0) ? (hEnt + (size_t)g * KPAD)
                             : (hAtt + (size_t)(g * 8 + (i - 1)) * KPAD);
    }
    __syncthreads();

#pragma unroll
    for (int it = 0; it < 10; ++it) {
        const int i = tid + 256 * it;
        const int row = i / 40, c8 = (i - row * 40) * 8;
        const uint4 v = *(const uint4*)(rowp[row] + c8);
        *(uint4*)&As[row * ASTR + c8] = v;
    }
    __syncthreads();

    float esa[4] = {0.f, 0.f, 0.f, 0.f};
    float eda[4] = {0.f, 0.f, 0.f, 0.f};

    for (int nt = 0; nt < 16; ++nt) {
        const int n0 = nt * 64;
        f32x4_t acc[4];
#pragma unroll
        for (int ni = 0; ni < 4; ++ni) acc[ni] = {0.f, 0.f, 0.f, 0.f};

        for (int k0 = 0; k0 < KPAD; k0 += 32) {
            const int rr_ = tid >> 2, c8 = (tid & 3) * 8;
            const uint4 bv = *(const uint4*)(WfcB + (size_t)(n0 + rr_) * KPAD + k0 + c8);
            __syncthreads();
            *(uint4*)&Bs[rr_ * 32 + c8] = bv;
            __syncthreads();

            const bf16x8_t af = *(const bf16x8_t*)&As[(w * 16 + lr) * ASTR + k0 + lk * 8];
#pragma unroll
            for (int ni = 0; ni < 4; ++ni) {
                const bf16x8_t bfr = *(const bf16x8_t*)&Bs[(ni * 16 + lr) * 32 + lk * 8];
                acc[ni] = __builtin_amdgcn_mfma_f32_16x16x32_bf16(af, bfr, acc[ni], 0, 0, 0);
            }
        }

#pragma unroll
        for (int ni = 0; ni < 4; ++ni) {
            const int n = n0 + ni * 16 + lr;
            const float aw = asW[n], dw = adW[n], bb = bfc[n];
#pragma unroll
            for (int r = 0; r < 4; ++r) {
                float v = acc[ni][r] + bb;
                v = v > 0.f ? v : 0.f;
                const int m = m0 + w * 16 + lk * 4 + r;
                nodes[(size_t)m * HDIM + n] = f2bf(v);
                esa[r] = fmaf(v, aw, esa[r]);
                eda[r] = fmaf(v, dw, eda[r]);
            }
        }
    }

    // reduce across the 16 lr lanes
#pragma unroll
    for (int r = 0; r < 4; ++r) {
        float s = esa[r], d = eda[r];
#pragma unroll
        for (int mask = 1; mask < 16; mask <<= 1) {
            s += __shfl_xor(s, mask, 64);
            d += __shfl_xor(d, mask, 64);
        }
        if (lr == 0) {
            const int m = m0 + w * 16 + lk * 4 + r;
            es[m] = s; ed[m] = d;
        }
    }
}

// =====================================================================
// Prep kernels
// =====================================================================
__global__ __launch_bounds__(256)
void convert_emb_kernel(const float* __restrict__ emb, bf16_t* __restrict__ embB)
{
    const int idx = blockIdx.x * 256 + threadIdx.x;    // over V_*40
    if (idx >= V_ * 40) return;
    const int row = idx / 40, c8 = (idx - row * 40) * 8;
    bf16_t o[8];
#pragma unroll
    for (int e = 0; e < 8; ++e) {
        const int c = c8 + e;
        o[e] = (c < WDIM) ? f2bf(emb[(size_t)row * WDIM + c]) : (bf16_t)0;
    }
    *(ushort4*)(embB + (size_t)row * KPAD + c8)     = *(ushort4*)&o[0];
    *(ushort4*)(embB + (size_t)row * KPAD + c8 + 4) = *(ushort4*)&o[4];
}

// W [3*300][300] fp32 -> [nrows][320] bf16 rows n=g*320+j (zero-padded)
__global__ __launch_bounds__(256)
void build_w3_kernel(const float* __restrict__ W, bf16_t* __restrict__ dst, int nrows)
{
    const int idx = blockIdx.x * 256 + threadIdx.x;
    if (idx >= nrows * KPAD) return;
    const int n = idx / KPAD, k = idx - n * KPAD;
    const int g = n / KPAD, j = n - g * KPAD;
    float v = 0.f;
    if (g < 3 && j < WDIM && k < WDIM)
        v = W[(size_t)(g * WDIM + j) * WDIM + k];
    dst[idx] = f2bf(v);
}

// W [3*300][300] fp32 -> dst[1024][320] bf16, INTERLEAVED rows n = 3*j + g
__global__ __launch_bounds__(256)
void build_w3i_kernel(const float* __restrict__ W, bf16_t* __restrict__ dst)
{
    const int idx = blockIdx.x * 256 + threadIdx.x;    // over 1024*320
    if (idx >= HDIM * KPAD) return;
    const int n = idx / KPAD, k = idx - n * KPAD;
    float v = 0.f;
    if (n < 960) {
        const int j = n / 3, g = n - j * 3;
        if (j < WDIM && k < WDIM)
            v = W[(size_t)(g * WDIM + j) * WDIM + k];
    }
    dst[idx] = f2bf(v);
}

__global__ __launch_bounds__(256)
void build_wfc_kernel(const float* __restrict__ Wfc, bf16_t* __restrict__ Wb)
{
    const int idx = blockIdx.x * 256 + threadIdx.x;    // over 1024*320
    if (idx >= HDIM * KPAD) return;
    const int n = idx / KPAD, k = idx - n * KPAD;
    Wb[idx] = f2bf(k < WDIM ? Wfc[(size_t)n * WDIM + k] : 0.f);
}

__global__ __launch_bounds__(256)
void build_wg_kernel(const float* __restrict__ Wg, bf16_t* __restrict__ Wb)
{
    const int idx = blockIdx.x * 256 + threadIdx.x;    // over 1024*1024
    Wb[idx] = f2bf(Wg[idx]);
}

// asW = a_src @ Wg, adW = a_dst @ Wg
__global__ __launch_bounds__(256)
void asw_kernel(const float* __restrict__ Wg,
                const float* __restrict__ a_src, const float* __restrict__ a_dst,
                float* __restrict__ asW, float* __restrict__ adW)
{
    const int k = blockIdx.x * 256 + threadIdx.x;
    float s = 0.f, d = 0.f;
    for (int n = 0; n < HDIM; ++n) {
        const float w = Wg[(size_t)n * HDIM + k];
        s = fmaf(a_src[n], w, s);
        d = fmaf(a_dst[n], w, d);
    }
    asW[k] = s; adW[k] = d;
}

// Row-0 star attention -> mixed[g] = sum_j alpha_j * nodes[g*9+j] (bf16)
__global__ __launch_bounds__(256)
void attn_mix_kernel(const bf16_t* __restrict__ nodes,
                     const float* __restrict__ es, const float* __restrict__ ed,
                     bf16_t* __restrict__ mixed)
{
    const int g = blockIdx.x;
    const float e0 = es[(size_t)g * NNODE];
    const float* edg = ed + (size_t)g * NNODE;

    float w[NNODE], mx = -1e30f;
#pragma unroll
    for (int j = 0; j < NNODE; ++j) {
        float v = e0 + edg[j];
        v = v >= 0.f ? v : 0.2f * v;
        w[j] = v; mx = fmaxf(mx, v);
    }
    float denom = 0.f;
#pragma unroll
    for (int j = 0; j < NNODE; ++j) { w[j] = expf(w[j] - mx); denom += w[j]; }
    const float inv = 1.f / denom;

    const int c = threadIdx.x * 4;
    float4 acc = {0.f, 0.f, 0.f, 0.f};
#pragma unroll
    for (int j = 0; j < NNODE; ++j) {
        const float a = w[j] * inv;
        const ushort4 h4 = *(const ushort4*)(nodes + (size_t)(g * NNODE + j) * HDIM + c);
        acc.x = fmaf(a, bf2f(h4.x), acc.x);
        acc.y = fmaf(a, bf2f(h4.y), acc.y);
        acc.z = fmaf(a, bf2f(h4.z), acc.z);
        acc.w = fmaf(a, bf2f(h4.w), acc.w);
    }
    ushort4 o;
    o.x = f2bf(acc.x); o.y = f2bf(acc.y); o.z = f2bf(acc.z); o.w = f2bf(acc.w);
    *(ushort4*)(mixed + (size_t)g * HDIM + c) = o;
}

// -------- workspace layout (~134 MiB; 157 MiB known-safe) --------
constexpr size_t SZ_EMBB  = (size_t)VP * KPAD * sizeof(bf16_t);      // 19.58 MB
constexpr size_t SZ_PROJ  = (size_t)VP * PROJW * sizeof(bf16_t);     // 62.65 MB
constexpr size_t SZ_HATT  = (size_t)GA * KPAD * sizeof(bf16_t);      // 20.97 MB x2
constexpr size_t SZ_HENT  = (size_t)G * KPAD * sizeof(bf16_t);       //  2.62 MB x2
constexpr size_t SZ_WIH3  = (size_t)HDIM * KPAD * sizeof(bf16_t);
constexpr size_t SZ_WHH3  = (size_t)960 * KPAD * sizeof(bf16_t);     //  0.61 MB (attr)
constexpr size_t SZ_WHH3E = (size_t)HDIM * KPAD * sizeof(bf16_t);    //  0.66 MB (ent, 1024 rows)
constexpr size_t SZ_WFC   = (size_t)HDIM * KPAD * sizeof(bf16_t);
constexpr size_t SZ_WG    = (size_t)HDIM * HDIM * sizeof(bf16_t);
constexpr size_t SZ_AW    = (size_t)HDIM * sizeof(float);
constexpr size_t SZ_VEC   = (size_t)MROWS * sizeof(float);
constexpr size_t SZ_NODE  = (size_t)MROWS * HDIM * sizeof(bf16_t);   // 75.5 MB
constexpr size_t SZ_MIX   = (size_t)G * HDIM * sizeof(bf16_t);
constexpr size_t WS_NEED  = SZ_EMBB + SZ_PROJ + 2 * SZ_HATT + 2 * SZ_HENT +
                            SZ_WIH3 + SZ_WHH3 + SZ_WHH3E + SZ_WFC + SZ_WG +
                            2 * SZ_AW + 2 * SZ_VEC;
static_assert(SZ_NODE <= SZ_EMBB + SZ_PROJ, "nodes overlays embB+proj");
static_assert(SZ_MIX  <= 2 * SZ_HATT,       "mixed overlays hAtt pair");

} // namespace

extern "C" void kernel_launch(void* const* d_in, const int* in_sizes, int n_in,
                              void* d_out, int out_size, void* d_ws, size_t ws_size,
                              hipStream_t stream)
{
    (void)in_sizes; (void)n_in; (void)out_size;
    if (ws_size < WS_NEED) return;   // clean absmax failure instead of fault

    const int*   ent_tok  = (const int*)  d_in[0];
    const int*   ent_len  = (const int*)  d_in[1];
    const int*   at_tok   = (const int*)  d_in[3];
    const int*   at_len   = (const int*)  d_in[4];
    const float* emb      = (const float*)d_in[6];
    const float* Wih_ent  = (const float*)d_in[7];
    const float* Whh_ent  = (const float*)d_in[8];
    const float* bih_ent  = (const float*)d_in[9];
    const float* bhh_ent  = (const float*)d_in[10];
    const float* Wih_attr = (const float*)d_in[11];
    const float* Whh_attr = (const float*)d_in[12];
    const float* bih_attr = (const float*)d_in[13];
    const float* bhh_attr = (const float*)d_in[14];
    const float* Wfc      = (const float*)d_in[15];
    const float* bfc      = (const float*)d_in[16];
    const float* Wg       = (const float*)d_in[17];
    const float* a_src    = (const float*)d_in[18];
    const float* a_dst    = (const float*)d_in[19];
    float* out = (float*)d_out;

    char* p = (char*)d_ws;
    bf16_t* embB  = (bf16_t*)p; p += SZ_EMBB;
    bf16_t* proj  = (bf16_t*)p; p += SZ_PROJ;
    bf16_t* hAtt[2];
    hAtt[0] = (bf16_t*)p; p += SZ_HATT;
    hAtt[1] = (bf16_t*)p; p += SZ_HATT;
    bf16_t* hEnt   = (bf16_t*)p; p += SZ_HENT;
    bf16_t* hEnt2  = (bf16_t*)p; p += SZ_HENT;
    bf16_t* Wih3   = (bf16_t*)p; p += SZ_WIH3;
    bf16_t* Whh3_a = (bf16_t*)p; p += SZ_WHH3;
    bf16_t* Whh3_e = (bf16_t*)p; p += SZ_WHH3E;
    bf16_t* WfcB   = (bf16_t*)p; p += SZ_WFC;
    bf16_t* WgB    = (bf16_t*)p; p += SZ_WG;
    float*  asW    = (float*)p;  p += SZ_AW;
    float*  adW    = (float*)p;  p += SZ_AW;
    float*  es     = (float*)p;  p += SZ_VEC;
    float*  ed     = (float*)p;  p += SZ_VEC;
    bf16_t* nodes  = embB;       // overlay: embB+proj dead after GRU loops
    bf16_t* mixed  = hAtt[0];    // overlay: hAtt dead after fc_nodes_esed

    // zero h ping-pong buffers (h0 = 0; pad cols must stay 0)
    hipMemsetAsync(hAtt[0], 0, SZ_HATT, stream);
    hipMemsetAsync(hAtt[1], 0, SZ_HATT, stream);
    hipMemsetAsync(hEnt,  0, SZ_HENT, stream);
    hipMemsetAsync(hEnt2, 0, SZ_HENT, stream);

    // prep
    convert_emb_kernel<<<dim3((V_ * 40 + 255) / 256), 256, 0, stream>>>(emb, embB);
    build_w3_kernel<<<dim3(HDIM * KPAD / 256), 256, 0, stream>>>(Wih_attr, Wih3, HDIM);
    build_w3_kernel<<<dim3(960 * KPAD / 256), 256, 0, stream>>>(Whh_attr, Whh3_a, 960);
    build_w3i_kernel<<<dim3(HDIM * KPAD / 256), 256, 0, stream>>>(Whh_ent, Whh3_e);
    build_wfc_kernel<<<dim3(HDIM * KPAD / 256), 256, 0, stream>>>(Wfc, WfcB);
    build_wg_kernel<<<dim3(HDIM * HDIM / 256), 256, 0, stream>>>(Wg, WgB);
    asw_kernel<<<dim3(HDIM / 256), 256, 0, stream>>>(Wg, a_src, a_dst, asW, adW);

    // attr vocab projection: proj[v] = embB[v] @ Wih3_attr^T (gate-block layout)
    mfma_gemm<0><<<dim3(VP / 128, PROJW / 128), 256, 0, stream>>>(
        embB, Wih3, proj, KPAD, KPAD, PROJW, KPAD);

    // attr GRU: T=4 (final h in hAtt[0])
    for (int t = 0; t < TA_; ++t)
        gru_attr_step<<<dim3(GA / 64), 256, 0, stream>>>(
            hAtt[t & 1], hAtt[(t + 1) & 1], Whh3_a, proj, at_tok, at_len,
            bih_attr, bhh_attr, TA_, t);

    // ent vocab projection: INTERLEAVED cols (n = 3j+g); overwrite proj
    build_w3i_kernel<<<dim3(HDIM * KPAD / 256), 256, 0, stream>>>(Wih_ent, Wih3);
    mfma_gemm<0><<<dim3(VP / 128, PROJW / 128), 256, 0, stream>>>(
        embB, Wih3, proj, KPAD, KPAD, PROJW, KPAD);

    // ent GRU: 8 fused GEMM+epilogue step launches, ping-pong h
    // t even: read hEnt, write hEnt2; t odd: reverse. Final (t=7) -> hEnt.
    bf16_t* hb[2] = { hEnt, hEnt2 };
    for (int t = 0; t < TE_; ++t)
        gru_step_fused<<<dim3(G / 128, 8), 512, 0, stream>>>(
            hb[t & 1], hb[(t + 1) & 1], Whh3_e, proj, ent_tok, ent_len,
            bih_ent, bhh_ent, TE_, t);

    // nodes = relu(h @ Wfc^T + bfc) with fused es/ed
    fc_nodes_esed<<<dim3(MROWS / 64), 256, 0, stream>>>(
        hEnt, hAtt[0], WfcB, bfc, asW, adW, nodes, es, ed);

    // row-0 softmax + node mixing
    attn_mix_kernel<<<dim3(G), 256, 0, stream>>>(nodes, es, ed, mixed);

    // out = elu(mixed @ Wg^T)
    mfma_gemm<2><<<dim3(G / 128, HDIM / 128), 256, 0, stream>>>(
        mixed, WgB, out, HDIM, HDIM, HDIM, HDIM);
}